// Round 1
// baseline (416.587 us; speedup 1.0000x reference)
//
#include <hip/hip_runtime.h>

// LearnedRouter: logits = x[T,H] @ W[E,H]^T ; scores = softmax(logits) ;
// (weights, indices) = top_k(scores, 2).
// T=16384, H=4096, E=8. Output flat: scores[T*8] | weights[T*2] | indices[T*2]
// (indices written as float values — harness reads whole buffer as fp32).
//
// Memory-bound on streaming x (256 MB). One wave per row: 64 lanes x 16
// float4 = 4096 floats. W (128 KB) stays L2-resident.

#define ROUTER_H 4096
#define ROUTER_E 8

__global__ __launch_bounds__(256) void learned_router_kernel(
    const float* __restrict__ x, const float* __restrict__ W,
    float* __restrict__ out_scores, float* __restrict__ out_w,
    float* __restrict__ out_idx, int n_rows)
{
    const int wave = (int)((blockIdx.x * blockDim.x + threadIdx.x) >> 6);
    const int lane = (int)(threadIdx.x & 63);
    if (wave >= n_rows) return;

    const float4* __restrict__ x4 = (const float4*)x + (size_t)wave * (ROUTER_H / 4);
    const float4* __restrict__ W4 = (const float4*)W;

    float acc[ROUTER_E];
#pragma unroll
    for (int e = 0; e < ROUTER_E; ++e) acc[e] = 0.f;

    // 4096 floats / row = 1024 float4; 64 lanes -> 16 iterations.
#pragma unroll 4
    for (int j = 0; j < (ROUTER_H / 4) / 64; ++j) {
        const int idx = j * 64 + lane;
        const float4 xv = x4[idx];
#pragma unroll
        for (int e = 0; e < ROUTER_E; ++e) {
            const float4 wv = W4[e * (ROUTER_H / 4) + idx];
            acc[e] += xv.x * wv.x + xv.y * wv.y + xv.z * wv.z + xv.w * wv.w;
        }
    }

    // Butterfly reduction across the 64-lane wave (wave = 64 on CDNA!).
#pragma unroll
    for (int off = 32; off > 0; off >>= 1) {
#pragma unroll
        for (int e = 0; e < ROUTER_E; ++e)
            acc[e] += __shfl_xor(acc[e], off, 64);
    }

    if (lane == 0) {
        // softmax over 8 logits (fp32, matches reference numerics)
        float m = acc[0];
#pragma unroll
        for (int e = 1; e < ROUTER_E; ++e) m = fmaxf(m, acc[e]);
        float p[ROUTER_E];
        float s = 0.f;
#pragma unroll
        for (int e = 0; e < ROUTER_E; ++e) { p[e] = __expf(acc[e] - m); s += p[e]; }
        const float inv = 1.f / s;
#pragma unroll
        for (int e = 0; e < ROUTER_E; ++e) p[e] *= inv;

        float4* os = (float4*)(out_scores + (size_t)wave * ROUTER_E);
        os[0] = make_float4(p[0], p[1], p[2], p[3]);
        os[1] = make_float4(p[4], p[5], p[6], p[7]);

        // top-2, lowest-index tie-break (matches jax.lax.top_k)
        int i0 = 0;
#pragma unroll
        for (int e = 1; e < ROUTER_E; ++e) if (p[e] > p[i0]) i0 = e;
        int i1 = (i0 == 0) ? 1 : 0;
#pragma unroll
        for (int e = 0; e < ROUTER_E; ++e) if (e != i0 && p[e] > p[i1]) i1 = e;

        *(float2*)(out_w + (size_t)wave * 2)   = make_float2(p[i0], p[i1]);
        *(float2*)(out_idx + (size_t)wave * 2) = make_float2((float)i0, (float)i1);
    }
}

extern "C" void kernel_launch(void* const* d_in, const int* in_sizes, int n_in,
                              void* d_out, int out_size, void* d_ws, size_t ws_size,
                              hipStream_t stream) {
    const float* x = (const float*)d_in[0];
    const float* W = (const float*)d_in[1];
    const int T = in_sizes[0] / ROUTER_H;            // 16384
    const int k = (out_size / T - ROUTER_E) / 2;     // 2 (layout check)
    (void)k; (void)n_in; (void)d_ws; (void)ws_size;

    float* out = (float*)d_out;
    float* out_scores = out;
    float* out_w   = out + (size_t)T * ROUTER_E;
    float* out_idx = out_w + (size_t)T * 2;

    // 256 threads = 4 waves = 4 rows per block
    const int rows_per_block = 4;
    const int grid = (T + rows_per_block - 1) / rows_per_block;
    learned_router_kernel<<<grid, 256, 0, stream>>>(x, W, out_scores, out_w, out_idx, T);
}

// Round 2
// 367.463 us; speedup vs baseline: 1.1337x; 1.1337x over previous
//
#include <hip/hip_runtime.h>

// LearnedRouter: logits = x[T,H] @ W[E,H]^T ; softmax ; top-2.
// T=16384, H=4096, E=8. Output flat: scores[T*8] | weights[T*2] | idx[T*2] (as fp32).
//
// R2: each wave processes R=4 rows -> per iter: 4 x-loads + 8 W-loads feed
// 128 FMAs (was 1+8 feeding 32). Cuts W L1/L2 re-read traffic 4x (2 GB ->
// 512 MB) and gives 4 independent acc chains/expert for latency hiding.

#define ROUTER_H 4096
#define ROUTER_E 8
#define ROWS_PER_WAVE 4

__global__ __launch_bounds__(256) void learned_router_kernel(
    const float* __restrict__ x, const float* __restrict__ W,
    float* __restrict__ out_scores, float* __restrict__ out_w,
    float* __restrict__ out_idx, int n_rows)
{
    const int wave = (int)((blockIdx.x * blockDim.x + threadIdx.x) >> 6);
    const int lane = (int)(threadIdx.x & 63);
    const int row0 = wave * ROWS_PER_WAVE;
    if (row0 >= n_rows) return;

    const float4* __restrict__ x4 = (const float4*)x;
    const float4* __restrict__ W4 = (const float4*)W;

    float acc[ROWS_PER_WAVE][ROUTER_E];
#pragma unroll
    for (int r = 0; r < ROWS_PER_WAVE; ++r)
#pragma unroll
        for (int e = 0; e < ROUTER_E; ++e) acc[r][e] = 0.f;

    // 1024 float4 per row / 64 lanes = 16 iterations.
#pragma unroll 2
    for (int j = 0; j < (ROUTER_H / 4) / 64; ++j) {
        const int idx = j * 64 + lane;
        float4 xv[ROWS_PER_WAVE];
#pragma unroll
        for (int r = 0; r < ROWS_PER_WAVE; ++r)
            xv[r] = x4[(size_t)(row0 + r) * (ROUTER_H / 4) + idx];
#pragma unroll
        for (int e = 0; e < ROUTER_E; ++e) {
            const float4 wv = W4[e * (ROUTER_H / 4) + idx];
#pragma unroll
            for (int r = 0; r < ROWS_PER_WAVE; ++r)
                acc[r][e] += xv[r].x * wv.x + xv[r].y * wv.y
                           + xv[r].z * wv.z + xv[r].w * wv.w;
        }
    }

    // Butterfly reduction across the 64-lane wave for all 32 accumulators.
#pragma unroll
    for (int off = 32; off > 0; off >>= 1) {
#pragma unroll
        for (int r = 0; r < ROWS_PER_WAVE; ++r)
#pragma unroll
            for (int e = 0; e < ROUTER_E; ++e)
                acc[r][e] += __shfl_xor(acc[r][e], off, 64);
    }

    if (lane == 0) {
#pragma unroll
        for (int r = 0; r < ROWS_PER_WAVE; ++r) {
            const int row = row0 + r;
            float m = acc[r][0];
#pragma unroll
            for (int e = 1; e < ROUTER_E; ++e) m = fmaxf(m, acc[r][e]);
            float p[ROUTER_E];
            float s = 0.f;
#pragma unroll
            for (int e = 0; e < ROUTER_E; ++e) { p[e] = __expf(acc[r][e] - m); s += p[e]; }
            const float inv = 1.f / s;
#pragma unroll
            for (int e = 0; e < ROUTER_E; ++e) p[e] *= inv;

            float4* os = (float4*)(out_scores + (size_t)row * ROUTER_E);
            os[0] = make_float4(p[0], p[1], p[2], p[3]);
            os[1] = make_float4(p[4], p[5], p[6], p[7]);

            // top-2, lowest-index tie-break (matches jax.lax.top_k)
            int i0 = 0;
#pragma unroll
            for (int e = 1; e < ROUTER_E; ++e) if (p[e] > p[i0]) i0 = e;
            int i1 = (i0 == 0) ? 1 : 0;
#pragma unroll
            for (int e = 0; e < ROUTER_E; ++e) if (e != i0 && p[e] > p[i1]) i1 = e;

            *(float2*)(out_w + (size_t)row * 2)   = make_float2(p[i0], p[i1]);
            *(float2*)(out_idx + (size_t)row * 2) = make_float2((float)i0, (float)i1);
        }
    }
}

extern "C" void kernel_launch(void* const* d_in, const int* in_sizes, int n_in,
                              void* d_out, int out_size, void* d_ws, size_t ws_size,
                              hipStream_t stream) {
    const float* x = (const float*)d_in[0];
    const float* W = (const float*)d_in[1];
    const int T = in_sizes[0] / ROUTER_H;            // 16384
    (void)n_in; (void)d_ws; (void)ws_size; (void)out_size;

    float* out = (float*)d_out;
    float* out_scores = out;
    float* out_w   = out + (size_t)T * ROUTER_E;
    float* out_idx = out_w + (size_t)T * 2;

    // 256 threads = 4 waves; each wave does 4 rows -> 16 rows/block.
    const int rows_per_block = 4 * ROWS_PER_WAVE;
    const int grid = (T + rows_per_block - 1) / rows_per_block;
    learned_router_kernel<<<grid, 256, 0, stream>>>(x, W, out_scores, out_w, out_idx, T);
}